// Round 8
// baseline (237.118 us; speedup 1.0000x reference)
//
#include <hip/hip_runtime.h>
#include <hip/hip_bf16.h>

// B=2048, N=512, D=8192.
// Pipeline (NO d_ws, NO atomics on global; scratch carved from d_out):
//   1. m_norms:     mm[n]=||m_n||^2 -> p-slot (dead after rescore)
//   2. gemm_coarse: bf16 MFMA dot partials, 128x128 tile, splitK=8 -> m+sd (32 MB).
//                   r16: REVERT to r13 (58us best-known). r15 (64^2 tiles, 8
//                   blocks/CU, Occ 58%) REGRESSED to 82us with MfmaUtil DOWN --
//                   occupancy disproven; time tracks staged L2 traffic (r15
//                   doubled it, +41% time). gemm floor ~58us for this structure;
//                   attention moves to the ~150us of rescore+ema (never in
//                   top-5 => each <=58us, combined ~= 2.5x gemm).
//   3. rescore:     coarse argmin + margin candidates; r16: Y row staged in LDS
//                   ONCE on the ncand>=2 path (was: each candidate wave re-read
//                   32KB Y from global -> halves exact-phase traffic).
//   4. ema_scatter: r16: grid N x 512thr (was (N,8) x 256thr): ONE ballot scan
//                   per cluster instead of 8 (saves 8x scan + 32MB assignF
//                   re-reads); block owns full 8192-float row; 4-member batched
//                   gathers; member order and EMA chain bit-identical.

#define Bb 2048
#define Nn 512
#define Dd 8192
#define MARGIN 12.0f
#define KC 8
#define KSTEPS 32   // (Dd/KC)/32

typedef __attribute__((ext_vector_type(4))) float f32x4;
typedef __attribute__((ext_vector_type(8))) short s16x8;
typedef __attribute__((ext_vector_type(2))) unsigned u32x2;

__device__ inline unsigned pack2(float lo, float hi) {
    return __builtin_amdgcn_perm(__float_as_uint(hi), __float_as_uint(lo), 0x07060302u);
}

__device__ inline void st4bf(unsigned short* dst, const float4 v) {
    u32x2 x;
    x[0] = pack2(v.x, v.y);
    x[1] = pack2(v.z, v.w);
    *(u32x2*)dst = x;          // 8B-aligned ds_write_b64
}

__device__ inline void ema4(float4& mcv, float4& scv, const float4 yv) {
#define EMA_C(c) { mcv.c = mcv.c * 0.001f + yv.c * 0.999f; \
                   float d_ = mcv.c - yv.c;                 \
                   scv.c = d_ * d_ * 0.001f + scv.c * 0.999f; }
    EMA_C(x) EMA_C(y) EMA_C(z) EMA_C(w)
#undef EMA_C
}

// ---------------- 1: m row norms ----------------
__global__ __launch_bounds__(256) void m_norms(const float* __restrict__ M,
                                               float* __restrict__ mm) {
    int n = blockIdx.x, t = threadIdx.x;
    const float4* r = (const float4*)(M + (size_t)n * Dd);
    float s = 0.f;
#pragma unroll
    for (int u = 0; u < 8; u++) {
        float4 v = r[t + 256 * u];
        s += v.x * v.x + v.y * v.y + v.z * v.z + v.w * v.w;
    }
    __shared__ float red[256];
    red[t] = s;
    __syncthreads();
    for (int off = 128; off > 0; off >>= 1) {
        if (t < off) red[t] += red[t + off];
        __syncthreads();
    }
    if (t == 0) mm[n] = red[0];
}

// ---------------- 2: coarse bf16 MFMA GEMM (dot only), splitK=8 ----------------
// r13 config: 1-D grid 512 blocks, 512 threads (8 waves). kc = bid&7 (XCD-
// pinned), ct = (bid>>3)&3, rt = bid>>5. Tile 128x128, 32 steps of BK=32.
// Coalesced staging (8 lanes cover a row's 128B), identity LDS layout,
// 2 named regsets (2-step-ahead), raw lgkm-only barriers.
__global__ __launch_bounds__(512, 4) void gemm_coarse(const float* __restrict__ Y,
                                                      const float* __restrict__ M,
                                                      float* __restrict__ part) {
    __shared__ __align__(16) unsigned short As[2][128 * 32];
    __shared__ __align__(16) unsigned short Bs[2][128 * 32];
    const int t = threadIdx.x;
    const int lane = t & 63;
    const int w = t >> 6;

    const int bid = blockIdx.x;
    const int kc = bid & 7;          // one kc chunk per XCD
    const int ct = (bid >> 3) & 3;
    const int rt = bid >> 5;

    const size_t ybase = (size_t)rt * 128 * Dd + (size_t)kc * (KSTEPS * 32);
    const size_t mbase = (size_t)ct * 128 * Dd + (size_t)kc * (KSTEPS * 32);

    // coalesced staging geometry
    const int rL = t >> 3;                 // rows rL and rL+64
    const int g4 = (t & 7) * 4;            // float col within 32-float panel
    const float* gA0 = Y + ybase + (size_t)rL * Dd + g4;
    const float* gB0 = M + mbase + (size_t)rL * Dd + g4;
    const int dst0 = rL * 32 + g4;         // bf16 elem offset (identity layout)

    const int wr0 = (w & 3) * 32, wc0 = (w >> 2) * 64;
    const int l15 = lane & 15, quad = lane >> 4;

    f32x4 acc[2][4];
#pragma unroll
    for (int i = 0; i < 2; i++)
#pragma unroll
        for (int j = 0; j < 4; j++) acc[i][j] = (f32x4)(0.0f);

    // two named staging register sets (static, never runtime-indexed)
    float4 aA0, aA1, aB0, aB1;     // set A
    float4 bA0, bA1, bB0, bB1;     // set B
    const size_t rowskip = (size_t)64 * Dd;

    auto loadsA = [&](int step) {
        const float* pa = gA0 + step * 32;
        const float* pb = gB0 + step * 32;
        aA0 = *(const float4*)pa;  aA1 = *(const float4*)(pa + rowskip);
        aB0 = *(const float4*)pb;  aB1 = *(const float4*)(pb + rowskip);
    };
    auto loadsB = [&](int step) {
        const float* pa = gA0 + step * 32;
        const float* pb = gB0 + step * 32;
        bA0 = *(const float4*)pa;  bA1 = *(const float4*)(pa + rowskip);
        bB0 = *(const float4*)pb;  bB1 = *(const float4*)(pb + rowskip);
    };
    auto writesA = [&](int buf) {
        st4bf(&As[buf][dst0],        aA0);
        st4bf(&As[buf][dst0 + 2048], aA1);    // +64 rows * 32 elems
        st4bf(&Bs[buf][dst0],        aB0);
        st4bf(&Bs[buf][dst0 + 2048], aB1);
    };
    auto writesB = [&](int buf) {
        st4bf(&As[buf][dst0],        bA0);
        st4bf(&As[buf][dst0 + 2048], bA1);
        st4bf(&Bs[buf][dst0],        bB0);
        st4bf(&Bs[buf][dst0 + 2048], bB1);
    };
    auto compute = [&](int buf) {
        s16x8 fa[2], fb[4];
#pragma unroll
        for (int ta = 0; ta < 2; ta++)
            fa[ta] = *(const s16x8*)(&As[buf][(wr0 + ta * 16 + l15) * 32 + quad * 8]);
#pragma unroll
        for (int tb = 0; tb < 4; tb++)
            fb[tb] = *(const s16x8*)(&Bs[buf][(wc0 + tb * 16 + l15) * 32 + quad * 8]);
#pragma unroll
        for (int i = 0; i < 2; i++)
#pragma unroll
            for (int j = 0; j < 4; j++)
                acc[i][j] = __builtin_amdgcn_mfma_f32_16x16x32_bf16(fa[i], fb[j], acc[i][j], 0, 0, 0);
    };

    // RAW barrier: ds_writes made visible with lgkmcnt(0) ONLY; staging loads
    // (VGPR-targeted) stay in flight across barriers via counted vmcnt.
#define BARRIER() do {                                          \
        asm volatile("s_waitcnt lgkmcnt(0)" ::: "memory");      \
        __builtin_amdgcn_s_barrier();                           \
    } while (0)

    loadsA(0);
    loadsB(1);
    writesA(0);
    BARRIER();
    for (int step = 0; step < KSTEPS; step += 2) {
        if (step + 2 < KSTEPS) loadsA(step + 2);
        compute(0);                  // step
        writesB(1);                  // step+1 data, loaded last iteration
        BARRIER();
        if (step + 3 < KSTEPS) loadsB(step + 3);
        compute(1);                  // step+1
        if (step + 2 < KSTEPS) writesA(0);   // step+2 data
        BARRIER();
    }
#undef BARRIER

    // store partials; C/D layout: col = lane&15, row = quad*4 + reg
    float* P = part + (size_t)kc * (Bb * Nn);
#pragma unroll
    for (int i = 0; i < 2; i++) {
        int rg = rt * 128 + wr0 + i * 16 + quad * 4;
#pragma unroll
        for (int j = 0; j < 4; j++) {
            int cg = ct * 128 + wc0 + j * 16 + l15;
#pragma unroll
            for (int r = 0; r < 4; r++)
                P[(size_t)(rg + r) * Nn + cg] = acc[i][j][r];
        }
    }
}

// ---------------- 3: coarse argmin + wave-parallel exact rescore ----------------
// r16: Y row staged into LDS once (only on the ncand>=2 path); candidate waves
// read Y from LDS and M from global (was: 32KB global Y re-read per candidate).
__global__ __launch_bounds__(256) void rescore(const float* __restrict__ Y,
                                               const float* __restrict__ M,
                                               const float* __restrict__ part,
                                               const float* __restrict__ mm,
                                               float* __restrict__ assignF) {
    __shared__ float redW[4];
    __shared__ int candList[Nn];
    __shared__ float candD2[Nn];
    __shared__ int candCnt;
    __shared__ __align__(16) float4 Ysh[Dd / 4];   // 32 KB
    int b = blockIdx.x, t = threadIdx.x, lane = t & 63, w = t >> 6;
    if (t == 0) candCnt = 0;

    int c0 = t, c1 = t + 256;
    float dot0 = 0.f, dot1 = 0.f;
#pragma unroll
    for (int k = 0; k < KC; k++) {
        dot0 += part[(size_t)k * (Bb * Nn) + (size_t)b * Nn + c0];
        dot1 += part[(size_t)k * (Bb * Nn) + (size_t)b * Nn + c1];
    }
    float d0 = mm[c0] - 2.0f * dot0;
    float d1 = mm[c1] - 2.0f * dot1;

    float mn = fminf(d0, d1);
#pragma unroll
    for (int off = 32; off > 0; off >>= 1) mn = fminf(mn, __shfl_xor(mn, off));
    if (lane == 0) redW[w] = mn;
    __syncthreads();
    float thresh = fminf(fminf(redW[0], redW[1]), fminf(redW[2], redW[3])) + MARGIN;

    if (d0 <= thresh) candList[atomicAdd(&candCnt, 1)] = c0;
    if (d1 <= thresh) candList[atomicAdd(&candCnt, 1)] = c1;
    __syncthreads();
    int ncand = candCnt;

    if (ncand == 1) {                 // uncontested coarse winner: exact dot unnecessary
        if (t == 0) assignF[b] = (float)candList[0];
        return;
    }

    // stage Y row once (coalesced), then candidate-per-wave exact dots
    const float4* yr = (const float4*)(Y + (size_t)b * Dd);
#pragma unroll
    for (int u = 0; u < 8; u++) Ysh[u * 256 + t] = yr[u * 256 + t];
    __syncthreads();

    for (int j = w; j < ncand; j += 4) {
        int c = candList[j];
        const float4* mr = (const float4*)(M + (size_t)c * Dd);
        float p = 0.f;
#pragma unroll 8
        for (int u = 0; u < 32; u++) {
            float4 yv = Ysh[u * 64 + lane];
            float4 mv = mr[u * 64 + lane];
            p += yv.x * mv.x + yv.y * mv.y + yv.z * mv.z + yv.w * mv.w;
        }
#pragma unroll
        for (int off = 32; off > 0; off >>= 1) p += __shfl_xor(p, off);
        if (lane == 0) candD2[j] = mm[c] - 2.0f * p;
    }
    __syncthreads();

    if (t == 0) {       // index-ordered scan: deterministic regardless of list order
        float bestV = 3.4e38f;
        int bestI = 0x3fffffff;
        for (int j = 0; j < ncand; j++) {
            float d2e = candD2[j];
            int c = candList[j];
            if (d2e < bestV || (d2e == bestV && c < bestI)) { bestV = d2e; bestI = c; }
        }
        assignF[b] = (float)bestI;
    }
}

// ---------------- 4: per-cluster sequential EMA, full row per block ------------
// r16: grid N, 512 threads (8 waves). ONE ballot scan per cluster (was 8).
// Thread t owns float4 slots {t, t+512, t+1024, t+1536} (coalesced passes).
// 4-member batched gathers; EMA member order identical to serial scan.
__global__ __launch_bounds__(512, 4) void ema_scatter(const float* __restrict__ Y,
                                                      const float* __restrict__ M0,
                                                      const float* __restrict__ SD0,
                                                      const float* __restrict__ P0,
                                                      const float* __restrict__ assignF,
                                                      float* __restrict__ m_out,
                                                      float* __restrict__ sd_out,
                                                      float* __restrict__ p_out) {
    __shared__ int lst[Bb];
    __shared__ int cnt8[8];
    int n = blockIdx.x, t = threadIdx.x, lane = t & 63, w = t >> 6;

    // 8 waves scan: wave w owns u-range [w*4, w*4+4) -> ordered sublist;
    // merge via prefix of per-wave counts (list identical to serial scan).
    int eqf[4], myidx[4];
    int cntW = 0;
#pragma unroll
    for (int k = 0; k < 4; k++) {
        int u = w * 4 + k;
        int zi = (int)assignF[u * 64 + lane];
        int eq = (zi == n) ? 1 : 0;
        unsigned long long mask = __ballot(eq != 0);
        eqf[k] = eq;
        myidx[k] = cntW + (int)__popcll(mask & ((1ull << lane) - 1ull));
        cntW += (int)__popcll(mask);
    }
    if (lane == 0) cnt8[w] = cntW;
    __syncthreads();
    int off0 = 0;
#pragma unroll
    for (int q = 0; q < 8; q++) off0 += (q < w) ? cnt8[q] : 0;
    int cnt = 0;
#pragma unroll
    for (int q = 0; q < 8; q++) cnt += cnt8[q];
#pragma unroll
    for (int k = 0; k < 4; k++)
        if (eqf[k]) lst[off0 + myidx[k]] = (w * 4 + k) * 64 + lane;
    if (t == 0) p_out[n] = P0[n] + (float)cnt;
    __syncthreads();

    const size_t base = (size_t)n * Dd;
    const float4* M4  = (const float4*)(M0 + base);
    const float4* S4  = (const float4*)(SD0 + base);
    float4 mc0 = M4[t], mc1 = M4[t + 512], mc2 = M4[t + 1024], mc3 = M4[t + 1536];
    float4 sc0 = S4[t], sc1 = S4[t + 512], sc2 = S4[t + 1024], sc3 = S4[t + 1536];

    int j = 0;
    for (; j + 4 <= cnt; j += 4) {       // 4-member batched gathers, exact order
        float4 yv[4][4];
#pragma unroll
        for (int q = 0; q < 4; q++) {
            const float4* yr = (const float4*)(Y + (size_t)lst[j + q] * Dd);
            yv[q][0] = yr[t];  yv[q][1] = yr[t + 512];
            yv[q][2] = yr[t + 1024];  yv[q][3] = yr[t + 1536];
        }
#pragma unroll
        for (int q = 0; q < 4; q++) {
            ema4(mc0, sc0, yv[q][0]);
            ema4(mc1, sc1, yv[q][1]);
            ema4(mc2, sc2, yv[q][2]);
            ema4(mc3, sc3, yv[q][3]);
        }
    }
    for (; j < cnt; j++) {
        const float4* yr = (const float4*)(Y + (size_t)lst[j] * Dd);
        float4 y0 = yr[t], y1 = yr[t + 512], y2 = yr[t + 1024], y3 = yr[t + 1536];
        ema4(mc0, sc0, y0);
        ema4(mc1, sc1, y1);
        ema4(mc2, sc2, y2);
        ema4(mc3, sc3, y3);
    }

    float4* Mo = (float4*)(m_out + base);
    float4* So = (float4*)(sd_out + base);
    Mo[t] = mc0;  Mo[t + 512] = mc1;  Mo[t + 1024] = mc2;  Mo[t + 1536] = mc3;
    So[t] = sc0;  So[t + 512] = sc1;  So[t + 1024] = sc2;  So[t + 1536] = sc3;
}

extern "C" void kernel_launch(void* const* d_in, const int* in_sizes, int n_in,
                              void* d_out, int out_size, void* d_ws, size_t ws_size,
                              hipStream_t stream) {
    const float* y  = (const float*)d_in[0];
    const float* m  = (const float*)d_in[1];
    const float* sd = (const float*)d_in[2];
    const float* p  = (const float*)d_in[3];

    float* out     = (float*)d_out;
    float* m_out   = out;                       // partials k=0..3 live here pre-rescore
    float* sd_out  = out + 4194304;             // partials k=4..7 live here pre-rescore
    float* p_out   = out + 8388608;             // also: mm norms (dead after rescore)
    float* assignF = out + 8389120;
    float* part    = out;                       // 8 x 1M floats = m+sd regions exactly

    m_norms    <<<Nn, 256, 0, stream>>>(m, p_out);
    gemm_coarse<<<dim3(512), 512, 0, stream>>>(y, m, part);
    rescore    <<<Bb, 256, 0, stream>>>(y, m, part, p_out, assignF);
    ema_scatter<<<Nn, 512, 0, stream>>>(y, m, sd, p, assignF, m_out, sd_out, p_out);
}

// Round 11
// 203.218 us; speedup vs baseline: 1.1668x; 1.1668x over previous
//
#include <hip/hip_runtime.h>
#include <hip/hip_bf16.h>

// B=2048, N=512, D=8192.
// Pipeline (scratch carved from d_out, per-block ownership):
//   1. m_norms:     mm[n]=||m_n||^2 -> p-slot (dead after rescore)
//   2. gemm_coarse: bf16 MFMA dot partials, 128x128 tile, splitK=8 -> m+sd (32 MB).
//                   r13 config, measured 58us floor for this structure.
//   3. rescore:     coarse argmin + margin candidates; exact f32 dots only if >=2
//                   candidates (Y read from global -- the 32KB row is L2-resident).
//   4. ema_closed:  CLOSED-FORM EMA (r19: third submit of the r17 theory; rounds
//                   9/10 died in the container layer with no counters. r19 removes
//                   the only novel structural pattern -- the divergent wave-0-only
//                   scan: now ALL 4 waves redundantly ballot-scan assignF; results
//                   are wave-uniform in every lane, so no sStat shared mem, no
//                   divergent branch, one less barrier. Semantics identical.)
//                   r16 measured ema at 63.7us with 7.5% occupancy (serial member
//                   chains + cluster-size tail). Math: decay 0.001 makes the scan
//                   analytically short --
//                   m = 0.001^k*m0 + 0.999*(y_last + 0.001*y_prev + 1e-6*y_prev2)
//                   (older terms <=1e-9); (m_i-y_i) = 0.001*(m_{i-1}-y_i) so all
//                   sd update terms <=1e-7 => sd = 0.999^k*sd0 (+<=3e-6);
//                   p = p0 + k. Total approx error <=1e-5, 4 orders below the
//                   stable 0.015625 absmax (1 bf16-ulp comparison artifact).
//                   Per cluster need only {count, last-3 member indices} from a
//                   64-lane ballot scan (top-3 set bits per 64-word, wave-uniform).
//                   Grid (N,4) x 256thr: uniform blocks, zero serial chains,
//                   traffic ~112MB -> ~20-25us.

#define Bb 2048
#define Nn 512
#define Dd 8192
#define MARGIN 12.0f
#define KC 8
#define KSTEPS 32   // (Dd/KC)/32

typedef __attribute__((ext_vector_type(4))) float f32x4;
typedef __attribute__((ext_vector_type(8))) short s16x8;
typedef __attribute__((ext_vector_type(2))) unsigned u32x2;

__device__ inline unsigned pack2(float lo, float hi) {
    return __builtin_amdgcn_perm(__float_as_uint(hi), __float_as_uint(lo), 0x07060302u);
}

__device__ inline void st4bf(unsigned short* dst, const float4 v) {
    u32x2 x;
    x[0] = pack2(v.x, v.y);
    x[1] = pack2(v.z, v.w);
    *(u32x2*)dst = x;          // 8B-aligned ds_write_b64
}

// ---------------- 1: m row norms ----------------
__global__ __launch_bounds__(256) void m_norms(const float* __restrict__ M,
                                               float* __restrict__ mm) {
    int n = blockIdx.x, t = threadIdx.x;
    const float4* r = (const float4*)(M + (size_t)n * Dd);
    float s = 0.f;
#pragma unroll
    for (int u = 0; u < 8; u++) {
        float4 v = r[t + 256 * u];
        s += v.x * v.x + v.y * v.y + v.z * v.z + v.w * v.w;
    }
    __shared__ float red[256];
    red[t] = s;
    __syncthreads();
    for (int off = 128; off > 0; off >>= 1) {
        if (t < off) red[t] += red[t + off];
        __syncthreads();
    }
    if (t == 0) mm[n] = red[0];
}

// ---------------- 2: coarse bf16 MFMA GEMM (dot only), splitK=8 ----------------
// r13 config: 1-D grid 512 blocks, 512 threads (8 waves). kc = bid&7 (XCD-
// pinned), ct = (bid>>3)&3, rt = bid>>5. Tile 128x128, 32 steps of BK=32.
// Coalesced staging (8 lanes cover a row's 128B), identity LDS layout,
// 2 named regsets (2-step-ahead), raw lgkm-only barriers.
__global__ __launch_bounds__(512, 4) void gemm_coarse(const float* __restrict__ Y,
                                                      const float* __restrict__ M,
                                                      float* __restrict__ part) {
    __shared__ __align__(16) unsigned short As[2][128 * 32];
    __shared__ __align__(16) unsigned short Bs[2][128 * 32];
    const int t = threadIdx.x;
    const int lane = t & 63;
    const int w = t >> 6;

    const int bid = blockIdx.x;
    const int kc = bid & 7;          // one kc chunk per XCD
    const int ct = (bid >> 3) & 3;
    const int rt = bid >> 5;

    const size_t ybase = (size_t)rt * 128 * Dd + (size_t)kc * (KSTEPS * 32);
    const size_t mbase = (size_t)ct * 128 * Dd + (size_t)kc * (KSTEPS * 32);

    // coalesced staging geometry
    const int rL = t >> 3;                 // rows rL and rL+64
    const int g4 = (t & 7) * 4;            // float col within 32-float panel
    const float* gA0 = Y + ybase + (size_t)rL * Dd + g4;
    const float* gB0 = M + mbase + (size_t)rL * Dd + g4;
    const int dst0 = rL * 32 + g4;         // bf16 elem offset (identity layout)

    const int wr0 = (w & 3) * 32, wc0 = (w >> 2) * 64;
    const int l15 = lane & 15, quad = lane >> 4;

    f32x4 acc[2][4];
#pragma unroll
    for (int i = 0; i < 2; i++)
#pragma unroll
        for (int j = 0; j < 4; j++) acc[i][j] = (f32x4)(0.0f);

    // two named staging register sets (static, never runtime-indexed)
    float4 aA0, aA1, aB0, aB1;     // set A
    float4 bA0, bA1, bB0, bB1;     // set B
    const size_t rowskip = (size_t)64 * Dd;

    auto loadsA = [&](int step) {
        const float* pa = gA0 + step * 32;
        const float* pb = gB0 + step * 32;
        aA0 = *(const float4*)pa;  aA1 = *(const float4*)(pa + rowskip);
        aB0 = *(const float4*)pb;  aB1 = *(const float4*)(pb + rowskip);
    };
    auto loadsB = [&](int step) {
        const float* pa = gA0 + step * 32;
        const float* pb = gB0 + step * 32;
        bA0 = *(const float4*)pa;  bA1 = *(const float4*)(pa + rowskip);
        bB0 = *(const float4*)pb;  bB1 = *(const float4*)(pb + rowskip);
    };
    auto writesA = [&](int buf) {
        st4bf(&As[buf][dst0],        aA0);
        st4bf(&As[buf][dst0 + 2048], aA1);    // +64 rows * 32 elems
        st4bf(&Bs[buf][dst0],        aB0);
        st4bf(&Bs[buf][dst0 + 2048], aB1);
    };
    auto writesB = [&](int buf) {
        st4bf(&As[buf][dst0],        bA0);
        st4bf(&As[buf][dst0 + 2048], bA1);
        st4bf(&Bs[buf][dst0],        bB0);
        st4bf(&Bs[buf][dst0 + 2048], bB1);
    };
    auto compute = [&](int buf) {
        s16x8 fa[2], fb[4];
#pragma unroll
        for (int ta = 0; ta < 2; ta++)
            fa[ta] = *(const s16x8*)(&As[buf][(wr0 + ta * 16 + l15) * 32 + quad * 8]);
#pragma unroll
        for (int tb = 0; tb < 4; tb++)
            fb[tb] = *(const s16x8*)(&Bs[buf][(wc0 + tb * 16 + l15) * 32 + quad * 8]);
#pragma unroll
        for (int i = 0; i < 2; i++)
#pragma unroll
            for (int j = 0; j < 4; j++)
                acc[i][j] = __builtin_amdgcn_mfma_f32_16x16x32_bf16(fa[i], fb[j], acc[i][j], 0, 0, 0);
    };

    // RAW barrier: ds_writes made visible with lgkmcnt(0) ONLY; staging loads
    // (VGPR-targeted) stay in flight across barriers via counted vmcnt.
#define BARRIER() do {                                          \
        asm volatile("s_waitcnt lgkmcnt(0)" ::: "memory");      \
        __builtin_amdgcn_s_barrier();                           \
    } while (0)

    loadsA(0);
    loadsB(1);
    writesA(0);
    BARRIER();
    for (int step = 0; step < KSTEPS; step += 2) {
        if (step + 2 < KSTEPS) loadsA(step + 2);
        compute(0);                  // step
        writesB(1);                  // step+1 data, loaded last iteration
        BARRIER();
        if (step + 3 < KSTEPS) loadsB(step + 3);
        compute(1);                  // step+1
        if (step + 2 < KSTEPS) writesA(0);   // step+2 data
        BARRIER();
    }
#undef BARRIER

    // store partials; C/D layout: col = lane&15, row = quad*4 + reg
    float* P = part + (size_t)kc * (Bb * Nn);
#pragma unroll
    for (int i = 0; i < 2; i++) {
        int rg = rt * 128 + wr0 + i * 16 + quad * 4;
#pragma unroll
        for (int j = 0; j < 4; j++) {
            int cg = ct * 128 + wc0 + j * 16 + l15;
#pragma unroll
            for (int r = 0; r < 4; r++)
                P[(size_t)(rg + r) * Nn + cg] = acc[i][j][r];
        }
    }
}

// ---------------- 3: coarse argmin + wave-parallel exact rescore ----------------
__global__ __launch_bounds__(256) void rescore(const float* __restrict__ Y,
                                               const float* __restrict__ M,
                                               const float* __restrict__ part,
                                               const float* __restrict__ mm,
                                               float* __restrict__ assignF) {
    __shared__ float redW[4];
    __shared__ int candList[Nn];
    __shared__ float candD2[Nn];
    __shared__ int candCnt;
    int b = blockIdx.x, t = threadIdx.x, lane = t & 63, w = t >> 6;
    if (t == 0) candCnt = 0;

    int c0 = t, c1 = t + 256;
    float dot0 = 0.f, dot1 = 0.f;
#pragma unroll
    for (int k = 0; k < KC; k++) {
        dot0 += part[(size_t)k * (Bb * Nn) + (size_t)b * Nn + c0];
        dot1 += part[(size_t)k * (Bb * Nn) + (size_t)b * Nn + c1];
    }
    float d0 = mm[c0] - 2.0f * dot0;
    float d1 = mm[c1] - 2.0f * dot1;

    float mn = fminf(d0, d1);
#pragma unroll
    for (int off = 32; off > 0; off >>= 1) mn = fminf(mn, __shfl_xor(mn, off));
    if (lane == 0) redW[w] = mn;
    __syncthreads();
    float thresh = fminf(fminf(redW[0], redW[1]), fminf(redW[2], redW[3])) + MARGIN;

    if (d0 <= thresh) candList[atomicAdd(&candCnt, 1)] = c0;
    if (d1 <= thresh) candList[atomicAdd(&candCnt, 1)] = c1;
    __syncthreads();
    int ncand = candCnt;

    if (ncand == 1) {                 // uncontested coarse winner: exact dot unnecessary
        if (t == 0) assignF[b] = (float)candList[0];
        return;
    }

    // each wave handles candidates j = w, w+4, ... (full-row dot per wave);
    // Y row is L2-resident after the first candidate -- no staging needed.
    const float4* yr = (const float4*)(Y + (size_t)b * Dd);
    for (int j = w; j < ncand; j += 4) {
        int c = candList[j];
        const float4* mr = (const float4*)(M + (size_t)c * Dd);
        float p = 0.f;
#pragma unroll 8
        for (int u = 0; u < 32; u++) {
            float4 yv = yr[u * 64 + lane];
            float4 mv = mr[u * 64 + lane];
            p += yv.x * mv.x + yv.y * mv.y + yv.z * mv.z + yv.w * mv.w;
        }
#pragma unroll
        for (int off = 32; off > 0; off >>= 1) p += __shfl_xor(p, off);
        if (lane == 0) candD2[j] = mm[c] - 2.0f * p;
    }
    __syncthreads();

    if (t == 0) {       // index-ordered scan: deterministic regardless of list order
        float bestV = 3.4e38f;
        int bestI = 0x3fffffff;
        for (int j = 0; j < ncand; j++) {
            float d2e = candD2[j];
            int c = candList[j];
            if (d2e < bestV || (d2e == bestV && c < bestI)) { bestV = d2e; bestI = c; }
        }
        assignF[b] = (float)bestI;
    }
}

// ---------------- 4: closed-form EMA (exact to <=1e-5) -------------------------
// Grid (Nn, 4), 256 threads. Block (n,s) owns 2048-float slice s.
// ALL 4 waves redundantly ballot-scan assignF for cluster n (identical masks ->
// identical wave-uniform {k, i1, i2, i3} in every lane; no shared mem, no
// divergence, no barrier). Within a 64-word, members ascend by lane; top set
// bits are the newest members.
// m_out = 0.001^k*m0 + 0.999*y[i1] + 0.000999*y[i2] + 9.99e-7*y[i3]
// sd_out = 0.999^k*sd0 ; p_out = p0 + k. Powers via binary exponentiation.
__global__ __launch_bounds__(256) void ema_closed(const float* __restrict__ Y,
                                                  const float* __restrict__ M0,
                                                  const float* __restrict__ SD0,
                                                  const float* __restrict__ P0,
                                                  const float* __restrict__ assignF,
                                                  float* __restrict__ m_out,
                                                  float* __restrict__ sd_out,
                                                  float* __restrict__ p_out) {
    const int n = blockIdx.x, s = blockIdx.y, t = threadIdx.x;
    const int lane = t & 63;

    int k = 0, i1 = -1, i2 = -1, i3 = -1;
    for (int u = 0; u < 32; u++) {
        int zi = (int)assignF[u * 64 + lane];
        unsigned long long mask = __ballot(zi == n);
        int c = (int)__popcll(mask);
        if (c > 0) {                           // wave-uniform branch (ballot result)
            int b1 = 63 - (int)__builtin_clzll(mask);
            if (c == 1) { i3 = i2; i2 = i1; i1 = u * 64 + b1; }
            else {
                unsigned long long m2 = mask & ~(1ull << b1);
                int b2 = 63 - (int)__builtin_clzll(m2);
                if (c == 2) { i3 = i1; i2 = u * 64 + b2; i1 = u * 64 + b1; }
                else {
                    unsigned long long m3 = m2 & ~(1ull << b2);
                    int b3 = 63 - (int)__builtin_clzll(m3);
                    i3 = u * 64 + b3; i2 = u * 64 + b2; i1 = u * 64 + b1;
                }
            }
            k += c;
        }
    }

    // binary pow: 0.001^k (underflow->0 for large k: term negligible) and 0.999^k
    float pwm = 1.f, pws = 1.f;
    {
        float bm = 0.001f, bs = 0.999f;
        int e = k;
        while (e) {
            if (e & 1) { pwm *= bm; pws *= bs; }
            bm *= bm; bs *= bs; e >>= 1;
        }
    }

    const size_t b4 = (size_t)n * (Dd / 4) + (size_t)s * 512;   // float4 units
    const f32x4* m4 = (const f32x4*)M0 + b4;
    const f32x4* s4 = (const f32x4*)SD0 + b4;
    f32x4* mo = (f32x4*)m_out + b4;
    f32x4* so = (f32x4*)sd_out + b4;

    f32x4 ma = m4[t] * pwm;
    f32x4 mb = m4[t + 256] * pwm;
    if (k >= 1) {
        const f32x4* y = (const f32x4*)Y + (size_t)i1 * (Dd / 4) + (size_t)s * 512;
        ma += y[t] * 0.999f;      mb += y[t + 256] * 0.999f;
    }
    if (k >= 2) {
        const f32x4* y = (const f32x4*)Y + (size_t)i2 * (Dd / 4) + (size_t)s * 512;
        ma += y[t] * 0.000999f;   mb += y[t + 256] * 0.000999f;
    }
    if (k >= 3) {
        const f32x4* y = (const f32x4*)Y + (size_t)i3 * (Dd / 4) + (size_t)s * 512;
        ma += y[t] * 9.99e-07f;   mb += y[t + 256] * 9.99e-07f;
    }
    mo[t] = ma;  mo[t + 256] = mb;
    so[t] = s4[t] * pws;  so[t + 256] = s4[t + 256] * pws;
    if (s == 0 && t == 0) p_out[n] = P0[n] + (float)k;
}

extern "C" void kernel_launch(void* const* d_in, const int* in_sizes, int n_in,
                              void* d_out, int out_size, void* d_ws, size_t ws_size,
                              hipStream_t stream) {
    const float* y  = (const float*)d_in[0];
    const float* m  = (const float*)d_in[1];
    const float* sd = (const float*)d_in[2];
    const float* p  = (const float*)d_in[3];

    float* out     = (float*)d_out;
    float* m_out   = out;                       // partials k=0..3 live here pre-rescore
    float* sd_out  = out + 4194304;             // partials k=4..7 live here pre-rescore
    float* p_out   = out + 8388608;             // also: mm norms (dead after rescore)
    float* assignF = out + 8389120;
    float* part    = out;                       // 8 x 1M floats = m+sd regions exactly

    m_norms    <<<Nn, 256, 0, stream>>>(m, p_out);
    gemm_coarse<<<dim3(512), 512, 0, stream>>>(y, m, part);
    rescore    <<<Bb, 256, 0, stream>>>(y, m, part, p_out, assignF);
    ema_closed <<<dim3(Nn, 4), 256, 0, stream>>>(y, m, sd, p, assignF, m_out, sd_out, p_out);
}

// Round 12
// 193.176 us; speedup vs baseline: 1.2275x; 1.0520x over previous
//
#include <hip/hip_runtime.h>
#include <hip/hip_bf16.h>

// B=2048, N=512, D=8192.
// Pipeline (scratch carved from d_out, per-block ownership):
//   1. m_norms:     mm[n]=||m_n||^2 -> p-slot (dead after rescore)
//   2. gemm_coarse: bf16 MFMA dot partials, 128x128 tile, splitK=8 -> m+sd (32 MB).
//                   r13 config, 59.5us pinned (7 rounds of structural changes all
//                   landed 58-60; every pipe <=16% busy -- unexplained floor).
//   3. rescore:     r20: ballot/prefix candidate build (no LDS atomics, one less
//                   barrier, deterministic c-ascending list). Coarse argmin +
//                   margin candidates; exact f32 dots only if >=2 candidates.
//   4. ema_closed:  closed-form EMA (validated r19: absmax unchanged; total -34us).
//                   r20: scan loads HOISTED -- 32 independent assignF loads into
//                   registers BEFORE the ballot chain (was: 32-deep dependent
//                   {load->ballot} chain ~8.6K cyc/block; now chain is pure VALU
//                   ~800 cyc). Remaining semantics identical:
//                   m = 0.001^k*m0 + 0.999*y[i1] + 0.000999*y[i2] + 9.99e-7*y[i3]
//                   sd = 0.999^k*sd0 ; p = p0 + k  (error <=1e-5, 4 orders below
//                   the 0.015625 absmax).

#define Bb 2048
#define Nn 512
#define Dd 8192
#define MARGIN 12.0f
#define KC 8
#define KSTEPS 32   // (Dd/KC)/32

typedef __attribute__((ext_vector_type(4))) float f32x4;
typedef __attribute__((ext_vector_type(8))) short s16x8;
typedef __attribute__((ext_vector_type(2))) unsigned u32x2;

__device__ inline unsigned pack2(float lo, float hi) {
    return __builtin_amdgcn_perm(__float_as_uint(hi), __float_as_uint(lo), 0x07060302u);
}

__device__ inline void st4bf(unsigned short* dst, const float4 v) {
    u32x2 x;
    x[0] = pack2(v.x, v.y);
    x[1] = pack2(v.z, v.w);
    *(u32x2*)dst = x;          // 8B-aligned ds_write_b64
}

// ---------------- 1: m row norms ----------------
__global__ __launch_bounds__(256) void m_norms(const float* __restrict__ M,
                                               float* __restrict__ mm) {
    int n = blockIdx.x, t = threadIdx.x;
    const float4* r = (const float4*)(M + (size_t)n * Dd);
    float s = 0.f;
#pragma unroll
    for (int u = 0; u < 8; u++) {
        float4 v = r[t + 256 * u];
        s += v.x * v.x + v.y * v.y + v.z * v.z + v.w * v.w;
    }
    __shared__ float red[256];
    red[t] = s;
    __syncthreads();
    for (int off = 128; off > 0; off >>= 1) {
        if (t < off) red[t] += red[t + off];
        __syncthreads();
    }
    if (t == 0) mm[n] = red[0];
}

// ---------------- 2: coarse bf16 MFMA GEMM (dot only), splitK=8 ----------------
// r13 config: 1-D grid 512 blocks, 512 threads (8 waves). kc = bid&7 (XCD-
// pinned), ct = (bid>>3)&3, rt = bid>>5. Tile 128x128, 32 steps of BK=32.
// Coalesced staging (8 lanes cover a row's 128B), identity LDS layout,
// 2 named regsets (2-step-ahead), raw lgkm-only barriers.
__global__ __launch_bounds__(512, 4) void gemm_coarse(const float* __restrict__ Y,
                                                      const float* __restrict__ M,
                                                      float* __restrict__ part) {
    __shared__ __align__(16) unsigned short As[2][128 * 32];
    __shared__ __align__(16) unsigned short Bs[2][128 * 32];
    const int t = threadIdx.x;
    const int lane = t & 63;
    const int w = t >> 6;

    const int bid = blockIdx.x;
    const int kc = bid & 7;          // one kc chunk per XCD
    const int ct = (bid >> 3) & 3;
    const int rt = bid >> 5;

    const size_t ybase = (size_t)rt * 128 * Dd + (size_t)kc * (KSTEPS * 32);
    const size_t mbase = (size_t)ct * 128 * Dd + (size_t)kc * (KSTEPS * 32);

    // coalesced staging geometry
    const int rL = t >> 3;                 // rows rL and rL+64
    const int g4 = (t & 7) * 4;            // float col within 32-float panel
    const float* gA0 = Y + ybase + (size_t)rL * Dd + g4;
    const float* gB0 = M + mbase + (size_t)rL * Dd + g4;
    const int dst0 = rL * 32 + g4;         // bf16 elem offset (identity layout)

    const int wr0 = (w & 3) * 32, wc0 = (w >> 2) * 64;
    const int l15 = lane & 15, quad = lane >> 4;

    f32x4 acc[2][4];
#pragma unroll
    for (int i = 0; i < 2; i++)
#pragma unroll
        for (int j = 0; j < 4; j++) acc[i][j] = (f32x4)(0.0f);

    // two named staging register sets (static, never runtime-indexed)
    float4 aA0, aA1, aB0, aB1;     // set A
    float4 bA0, bA1, bB0, bB1;     // set B
    const size_t rowskip = (size_t)64 * Dd;

    auto loadsA = [&](int step) {
        const float* pa = gA0 + step * 32;
        const float* pb = gB0 + step * 32;
        aA0 = *(const float4*)pa;  aA1 = *(const float4*)(pa + rowskip);
        aB0 = *(const float4*)pb;  aB1 = *(const float4*)(pb + rowskip);
    };
    auto loadsB = [&](int step) {
        const float* pa = gA0 + step * 32;
        const float* pb = gB0 + step * 32;
        bA0 = *(const float4*)pa;  bA1 = *(const float4*)(pa + rowskip);
        bB0 = *(const float4*)pb;  bB1 = *(const float4*)(pb + rowskip);
    };
    auto writesA = [&](int buf) {
        st4bf(&As[buf][dst0],        aA0);
        st4bf(&As[buf][dst0 + 2048], aA1);    // +64 rows * 32 elems
        st4bf(&Bs[buf][dst0],        aB0);
        st4bf(&Bs[buf][dst0 + 2048], aB1);
    };
    auto writesB = [&](int buf) {
        st4bf(&As[buf][dst0],        bA0);
        st4bf(&As[buf][dst0 + 2048], bA1);
        st4bf(&Bs[buf][dst0],        bB0);
        st4bf(&Bs[buf][dst0 + 2048], bB1);
    };
    auto compute = [&](int buf) {
        s16x8 fa[2], fb[4];
#pragma unroll
        for (int ta = 0; ta < 2; ta++)
            fa[ta] = *(const s16x8*)(&As[buf][(wr0 + ta * 16 + l15) * 32 + quad * 8]);
#pragma unroll
        for (int tb = 0; tb < 4; tb++)
            fb[tb] = *(const s16x8*)(&Bs[buf][(wc0 + tb * 16 + l15) * 32 + quad * 8]);
#pragma unroll
        for (int i = 0; i < 2; i++)
#pragma unroll
            for (int j = 0; j < 4; j++)
                acc[i][j] = __builtin_amdgcn_mfma_f32_16x16x32_bf16(fa[i], fb[j], acc[i][j], 0, 0, 0);
    };

    // RAW barrier: ds_writes made visible with lgkmcnt(0) ONLY; staging loads
    // (VGPR-targeted) stay in flight across barriers via counted vmcnt.
#define BARRIER() do {                                          \
        asm volatile("s_waitcnt lgkmcnt(0)" ::: "memory");      \
        __builtin_amdgcn_s_barrier();                           \
    } while (0)

    loadsA(0);
    loadsB(1);
    writesA(0);
    BARRIER();
    for (int step = 0; step < KSTEPS; step += 2) {
        if (step + 2 < KSTEPS) loadsA(step + 2);
        compute(0);                  // step
        writesB(1);                  // step+1 data, loaded last iteration
        BARRIER();
        if (step + 3 < KSTEPS) loadsB(step + 3);
        compute(1);                  // step+1
        if (step + 2 < KSTEPS) writesA(0);   // step+2 data
        BARRIER();
    }
#undef BARRIER

    // store partials; C/D layout: col = lane&15, row = quad*4 + reg
    float* P = part + (size_t)kc * (Bb * Nn);
#pragma unroll
    for (int i = 0; i < 2; i++) {
        int rg = rt * 128 + wr0 + i * 16 + quad * 4;
#pragma unroll
        for (int j = 0; j < 4; j++) {
            int cg = ct * 128 + wc0 + j * 16 + l15;
#pragma unroll
            for (int r = 0; r < 4; r++)
                P[(size_t)(rg + r) * Nn + cg] = acc[i][j][r];
        }
    }
}

// ---------------- 3: coarse argmin + wave-parallel exact rescore ----------------
// r20: candidate list built via ballot + cross-wave prefix (no LDS atomics, one
// less barrier). List is c-ascending; final scan picks (min d2, lowest c) --
// semantics identical to the previous index-ordered scan.
__global__ __launch_bounds__(256) void rescore(const float* __restrict__ Y,
                                               const float* __restrict__ M,
                                               const float* __restrict__ part,
                                               const float* __restrict__ mm,
                                               float* __restrict__ assignF) {
    __shared__ float redW[4];
    __shared__ int cntW[8];
    __shared__ int candList[Nn];
    __shared__ float candD2[Nn];
    int b = blockIdx.x, t = threadIdx.x, lane = t & 63, w = t >> 6;

    int c0 = t, c1 = t + 256;
    float dot0 = 0.f, dot1 = 0.f;
#pragma unroll
    for (int k = 0; k < KC; k++) {
        dot0 += part[(size_t)k * (Bb * Nn) + (size_t)b * Nn + c0];
        dot1 += part[(size_t)k * (Bb * Nn) + (size_t)b * Nn + c1];
    }
    float d0 = mm[c0] - 2.0f * dot0;
    float d1 = mm[c1] - 2.0f * dot1;

    float mn = fminf(d0, d1);
#pragma unroll
    for (int off = 32; off > 0; off >>= 1) mn = fminf(mn, __shfl_xor(mn, off));
    if (lane == 0) redW[w] = mn;
    __syncthreads();
    float thresh = fminf(fminf(redW[0], redW[1]), fminf(redW[2], redW[3])) + MARGIN;

    // ballot/prefix candidate build: group order (c0 waves 0-3, then c1 waves 0-3)
    bool f0 = (d0 <= thresh), f1 = (d1 <= thresh);
    unsigned long long mk0 = __ballot(f0), mk1 = __ballot(f1);
    if (lane == 0) { cntW[w] = (int)__popcll(mk0); cntW[4 + w] = (int)__popcll(mk1); }
    __syncthreads();
    int ncand = 0;
#pragma unroll
    for (int q = 0; q < 8; q++) ncand += cntW[q];
    int base0 = 0, baseF1 = cntW[0] + cntW[1] + cntW[2] + cntW[3];
#pragma unroll
    for (int q = 0; q < 4; q++) base0 += (q < w) ? cntW[q] : 0;
    int base1 = baseF1;
#pragma unroll
    for (int q = 0; q < 4; q++) base1 += (q < w) ? cntW[4 + q] : 0;
    unsigned long long ltm = (1ull << lane) - 1ull;
    if (f0) candList[base0 + (int)__popcll(mk0 & ltm)] = c0;
    if (f1) candList[base1 + (int)__popcll(mk1 & ltm)] = c1;
    __syncthreads();

    if (ncand == 1) {                 // uncontested coarse winner: exact dot unnecessary
        if (t == 0) assignF[b] = (float)candList[0];
        return;
    }

    // each wave handles candidates j = w, w+4, ... (full-row dot per wave);
    // Y row is L2-resident after the first candidate -- no staging needed.
    const float4* yr = (const float4*)(Y + (size_t)b * Dd);
    for (int j = w; j < ncand; j += 4) {
        int c = candList[j];
        const float4* mr = (const float4*)(M + (size_t)c * Dd);
        float p = 0.f;
#pragma unroll 8
        for (int u = 0; u < 32; u++) {
            float4 yv = yr[u * 64 + lane];
            float4 mv = mr[u * 64 + lane];
            p += yv.x * mv.x + yv.y * mv.y + yv.z * mv.z + yv.w * mv.w;
        }
#pragma unroll
        for (int off = 32; off > 0; off >>= 1) p += __shfl_xor(p, off);
        if (lane == 0) candD2[j] = mm[c] - 2.0f * p;
    }
    __syncthreads();

    if (t == 0) {       // index-ordered scan: deterministic regardless of list order
        float bestV = 3.4e38f;
        int bestI = 0x3fffffff;
        for (int j = 0; j < ncand; j++) {
            float d2e = candD2[j];
            int c = candList[j];
            if (d2e < bestV || (d2e == bestV && c < bestI)) { bestV = d2e; bestI = c; }
        }
        assignF[b] = (float)bestI;
    }
}

// ---------------- 4: closed-form EMA (exact to <=1e-5) -------------------------
// Grid (Nn, 4), 256 threads. Block (n,s) owns 2048-float slice s.
// All 4 waves redundantly scan assignF (wave-uniform results, no shared mem).
// r20: the 32 assignF words are loaded into REGISTERS first (independent,
// parallel-issued loads), then the ballot chain runs on registers -- the
// 32-deep dependent {load->ballot} chain becomes pure VALU.
// m_out = 0.001^k*m0 + 0.999*y[i1] + 0.000999*y[i2] + 9.99e-7*y[i3]
// sd_out = 0.999^k*sd0 ; p_out = p0 + k. Powers via binary exponentiation.
__global__ __launch_bounds__(256) void ema_closed(const float* __restrict__ Y,
                                                  const float* __restrict__ M0,
                                                  const float* __restrict__ SD0,
                                                  const float* __restrict__ P0,
                                                  const float* __restrict__ assignF,
                                                  float* __restrict__ m_out,
                                                  float* __restrict__ sd_out,
                                                  float* __restrict__ p_out) {
    const int n = blockIdx.x, s = blockIdx.y, t = threadIdx.x;
    const int lane = t & 63;

    // hoisted loads: fully unrolled -> static indices -> registers (rule #20)
    int ziv[32];
#pragma unroll
    for (int u = 0; u < 32; u++) ziv[u] = (int)assignF[u * 64 + lane];

    int k = 0, i1 = -1, i2 = -1, i3 = -1;
#pragma unroll
    for (int u = 0; u < 32; u++) {
        unsigned long long mask = __ballot(ziv[u] == n);
        int c = (int)__popcll(mask);
        if (c > 0) {                           // wave-uniform branch (ballot result)
            int b1 = 63 - (int)__builtin_clzll(mask);
            if (c == 1) { i3 = i2; i2 = i1; i1 = u * 64 + b1; }
            else {
                unsigned long long m2 = mask & ~(1ull << b1);
                int b2 = 63 - (int)__builtin_clzll(m2);
                if (c == 2) { i3 = i1; i2 = u * 64 + b2; i1 = u * 64 + b1; }
                else {
                    unsigned long long m3 = m2 & ~(1ull << b2);
                    int b3 = 63 - (int)__builtin_clzll(m3);
                    i3 = u * 64 + b3; i2 = u * 64 + b2; i1 = u * 64 + b1;
                }
            }
            k += c;
        }
    }

    // binary pow: 0.001^k (underflow->0 for large k: term negligible) and 0.999^k
    float pwm = 1.f, pws = 1.f;
    {
        float bm = 0.001f, bs = 0.999f;
        int e = k;
        while (e) {
            if (e & 1) { pwm *= bm; pws *= bs; }
            bm *= bm; bs *= bs; e >>= 1;
        }
    }

    const size_t b4 = (size_t)n * (Dd / 4) + (size_t)s * 512;   // float4 units
    const f32x4* m4 = (const f32x4*)M0 + b4;
    const f32x4* s4 = (const f32x4*)SD0 + b4;
    f32x4* mo = (f32x4*)m_out + b4;
    f32x4* so = (f32x4*)sd_out + b4;

    f32x4 ma = m4[t] * pwm;
    f32x4 mb = m4[t + 256] * pwm;
    if (k >= 1) {
        const f32x4* y = (const f32x4*)Y + (size_t)i1 * (Dd / 4) + (size_t)s * 512;
        ma += y[t] * 0.999f;      mb += y[t + 256] * 0.999f;
    }
    if (k >= 2) {
        const f32x4* y = (const f32x4*)Y + (size_t)i2 * (Dd / 4) + (size_t)s * 512;
        ma += y[t] * 0.000999f;   mb += y[t + 256] * 0.000999f;
    }
    if (k >= 3) {
        const f32x4* y = (const f32x4*)Y + (size_t)i3 * (Dd / 4) + (size_t)s * 512;
        ma += y[t] * 9.99e-07f;   mb += y[t + 256] * 9.99e-07f;
    }
    mo[t] = ma;  mo[t + 256] = mb;
    so[t] = s4[t] * pws;  so[t + 256] = s4[t + 256] * pws;
    if (s == 0 && t == 0) p_out[n] = P0[n] + (float)k;
}

extern "C" void kernel_launch(void* const* d_in, const int* in_sizes, int n_in,
                              void* d_out, int out_size, void* d_ws, size_t ws_size,
                              hipStream_t stream) {
    const float* y  = (const float*)d_in[0];
    const float* m  = (const float*)d_in[1];
    const float* sd = (const float*)d_in[2];
    const float* p  = (const float*)d_in[3];

    float* out     = (float*)d_out;
    float* m_out   = out;                       // partials k=0..3 live here pre-rescore
    float* sd_out  = out + 4194304;             // partials k=4..7 live here pre-rescore
    float* p_out   = out + 8388608;             // also: mm norms (dead after rescore)
    float* assignF = out + 8389120;
    float* part    = out;                       // 8 x 1M floats = m+sd regions exactly

    m_norms    <<<Nn, 256, 0, stream>>>(m, p_out);
    gemm_coarse<<<dim3(512), 512, 0, stream>>>(y, m, part);
    rescore    <<<Bb, 256, 0, stream>>>(y, m, part, p_out, assignF);
    ema_closed <<<dim3(Nn, 4), 256, 0, stream>>>(y, m, sd, p, assignF, m_out, sd_out, p_out);
}

// Round 13
// 188.037 us; speedup vs baseline: 1.2610x; 1.0273x over previous
//
#include <hip/hip_runtime.h>
#include <hip/hip_bf16.h>

// B=2048, N=512, D=8192.
// Pipeline (scratch carved from d_out, per-block ownership):
//   1. m_norms:     mm[n]=||m_n||^2 -> p-slot (dead after rescore)
//   2. gemm_coarse: bf16 MFMA dot partials, splitK=8 -> m+sd (32 MB).
//                   r21: 256x128 TILE (traffic test). Nine rounds pinned at
//                   58-60us with ALL pipes <=16%: the only model fitting every
//                   datapoint is STAGED-TRAFFIC bound via L3 -- per-XCD working
//                   set (8MB Y + 2MB M) > 4MB L2, so panel re-reads hit Infinity
//                   Cache; 536 MB staged / 59.5us = 9 TB/s == plausible L3 BW;
//                   r15 (2x traffic) = +38% time; BK/barrier/occupancy changes
//                   (traffic-neutral) = flat. This round: tile 256x128, grid
//                   8rt x 4ct x 8kc = 256 blocks x 1024 thr (16 waves, 4/SIMD,
//                   same waves/CU) -> staged 402 MB (x0.75). Same coalesced
//                   staging, identity LDS, 2-regset 2-ahead pipeline, raw lgkm
//                   barrier, same K order (partials bit-identical).
//   3. rescore:     ballot/prefix candidate build; coarse argmin + margin cands;
//                   exact f32 dots (candidate-per-wave) only if >=2 candidates.
//   4. ema_closed:  closed-form EMA (validated: absmax unchanged).
//                   m = 0.001^k*m0 + 0.999*y[i1] + 0.000999*y[i2] + 9.99e-7*y[i3]
//                   sd = 0.999^k*sd0 ; p = p0 + k  (error <=1e-5). Hoisted-load
//                   ballot scan (r20, -10us total).

#define Bb 2048
#define Nn 512
#define Dd 8192
#define MARGIN 12.0f
#define KC 8
#define KSTEPS 32   // (Dd/KC)/32

typedef __attribute__((ext_vector_type(4))) float f32x4;
typedef __attribute__((ext_vector_type(8))) short s16x8;
typedef __attribute__((ext_vector_type(2))) unsigned u32x2;

__device__ inline unsigned pack2(float lo, float hi) {
    return __builtin_amdgcn_perm(__float_as_uint(hi), __float_as_uint(lo), 0x07060302u);
}

__device__ inline void st4bf(unsigned short* dst, const float4 v) {
    u32x2 x;
    x[0] = pack2(v.x, v.y);
    x[1] = pack2(v.z, v.w);
    *(u32x2*)dst = x;          // 8B-aligned ds_write_b64
}

// ---------------- 1: m row norms ----------------
__global__ __launch_bounds__(256) void m_norms(const float* __restrict__ M,
                                               float* __restrict__ mm) {
    int n = blockIdx.x, t = threadIdx.x;
    const float4* r = (const float4*)(M + (size_t)n * Dd);
    float s = 0.f;
#pragma unroll
    for (int u = 0; u < 8; u++) {
        float4 v = r[t + 256 * u];
        s += v.x * v.x + v.y * v.y + v.z * v.z + v.w * v.w;
    }
    __shared__ float red[256];
    red[t] = s;
    __syncthreads();
    for (int off = 128; off > 0; off >>= 1) {
        if (t < off) red[t] += red[t + off];
        __syncthreads();
    }
    if (t == 0) mm[n] = red[0];
}

// ---------------- 2: coarse bf16 MFMA GEMM (dot only), splitK=8 ----------------
// r21: 1-D grid 256 blocks, 1024 threads (16 waves). kc = bid&7 (XCD-pinned),
// ct = (bid>>3)&3, rt = bid>>5. Tile 256x128, 32 steps of BK=32.
// Wave w (4x4 grid): rows (w&3)*64..+63, cols (w>>2)*32..+31; acc[4][2].
// Staging: thread t -> A rows {t>>3, t>>3+128} + B row {t>>3}, float4 at col
// (t&7)*4 (8 lanes cover a row's 128B contiguously). Identity LDS layout
// (wave b128 frag reads cover a 1KB region exactly once: conflict-free).
// 2 named regsets (2-step-ahead), raw lgkm-only barriers.
__global__ __launch_bounds__(1024, 4) void gemm_coarse(const float* __restrict__ Y,
                                                       const float* __restrict__ M,
                                                       float* __restrict__ part) {
    __shared__ __align__(16) unsigned short As[2][256 * 32];
    __shared__ __align__(16) unsigned short Bs[2][128 * 32];
    const int t = threadIdx.x;
    const int lane = t & 63;
    const int w = t >> 6;

    const int bid = blockIdx.x;
    const int kc = bid & 7;          // one kc chunk per XCD
    const int ct = (bid >> 3) & 3;
    const int rt = bid >> 5;

    const size_t ybase = (size_t)rt * 256 * Dd + (size_t)kc * (KSTEPS * 32);
    const size_t mbase = (size_t)ct * 128 * Dd + (size_t)kc * (KSTEPS * 32);

    // coalesced staging geometry: A rows rL, rL+128; B row rL; col (t&7)*4
    const int rL = t >> 3;                 // 0..127
    const int c4 = (t & 7) * 4;
    const float* gA0 = Y + ybase + (size_t)rL * Dd + c4;
    const float* gB0 = M + mbase + (size_t)rL * Dd + c4;
    const int dst0 = rL * 32 + c4;         // bf16 elem offset (identity layout)
    const size_t rowskipA = (size_t)128 * Dd;

    const int wr0 = (w & 3) * 64, wc0 = (w >> 2) * 32;
    const int l15 = lane & 15, quad = lane >> 4;

    f32x4 acc[4][2];
#pragma unroll
    for (int i = 0; i < 4; i++)
#pragma unroll
        for (int j = 0; j < 2; j++) acc[i][j] = (f32x4)(0.0f);

    // two named staging register sets (static, never runtime-indexed)
    float4 aA0, aA1, aB0;          // set A
    float4 bA0, bA1, bB0;          // set B

    auto loadsA = [&](int step) {
        const float* pa = gA0 + step * 32;
        const float* pb = gB0 + step * 32;
        aA0 = *(const float4*)pa;  aA1 = *(const float4*)(pa + rowskipA);
        aB0 = *(const float4*)pb;
    };
    auto loadsB = [&](int step) {
        const float* pa = gA0 + step * 32;
        const float* pb = gB0 + step * 32;
        bA0 = *(const float4*)pa;  bA1 = *(const float4*)(pa + rowskipA);
        bB0 = *(const float4*)pb;
    };
    auto writesA = [&](int buf) {
        st4bf(&As[buf][dst0],        aA0);
        st4bf(&As[buf][dst0 + 4096], aA1);    // +128 rows * 32 elems
        st4bf(&Bs[buf][dst0],        aB0);
    };
    auto writesB = [&](int buf) {
        st4bf(&As[buf][dst0],        bA0);
        st4bf(&As[buf][dst0 + 4096], bA1);
        st4bf(&Bs[buf][dst0],        bB0);
    };
    auto compute = [&](int buf) {
        s16x8 fa[4], fb[2];
#pragma unroll
        for (int ta = 0; ta < 4; ta++)
            fa[ta] = *(const s16x8*)(&As[buf][(wr0 + ta * 16 + l15) * 32 + quad * 8]);
#pragma unroll
        for (int tb = 0; tb < 2; tb++)
            fb[tb] = *(const s16x8*)(&Bs[buf][(wc0 + tb * 16 + l15) * 32 + quad * 8]);
#pragma unroll
        for (int i = 0; i < 4; i++)
#pragma unroll
            for (int j = 0; j < 2; j++)
                acc[i][j] = __builtin_amdgcn_mfma_f32_16x16x32_bf16(fa[i], fb[j], acc[i][j], 0, 0, 0);
    };

    // RAW barrier: ds_writes made visible with lgkmcnt(0) ONLY; staging loads
    // (VGPR-targeted) stay in flight across barriers via counted vmcnt.
#define BARRIER() do {                                          \
        asm volatile("s_waitcnt lgkmcnt(0)" ::: "memory");      \
        __builtin_amdgcn_s_barrier();                           \
    } while (0)

    loadsA(0);
    loadsB(1);
    writesA(0);
    BARRIER();
    for (int step = 0; step < KSTEPS; step += 2) {
        if (step + 2 < KSTEPS) loadsA(step + 2);
        compute(0);                  // step
        writesB(1);                  // step+1 data, loaded last iteration
        BARRIER();
        if (step + 3 < KSTEPS) loadsB(step + 3);
        compute(1);                  // step+1
        if (step + 2 < KSTEPS) writesA(0);   // step+2 data
        BARRIER();
    }
#undef BARRIER

    // store partials; C/D layout: col = lane&15, row = quad*4 + reg
    float* P = part + (size_t)kc * (Bb * Nn);
#pragma unroll
    for (int i = 0; i < 4; i++) {
        int rg = rt * 256 + wr0 + i * 16 + quad * 4;
#pragma unroll
        for (int j = 0; j < 2; j++) {
            int cg = ct * 128 + wc0 + j * 16 + l15;
#pragma unroll
            for (int r = 0; r < 4; r++)
                P[(size_t)(rg + r) * Nn + cg] = acc[i][j][r];
        }
    }
}

// ---------------- 3: coarse argmin + wave-parallel exact rescore ----------------
// Candidate list built via ballot + cross-wave prefix (no LDS atomics).
__global__ __launch_bounds__(256) void rescore(const float* __restrict__ Y,
                                               const float* __restrict__ M,
                                               const float* __restrict__ part,
                                               const float* __restrict__ mm,
                                               float* __restrict__ assignF) {
    __shared__ float redW[4];
    __shared__ int cntW[8];
    __shared__ int candList[Nn];
    __shared__ float candD2[Nn];
    int b = blockIdx.x, t = threadIdx.x, lane = t & 63, w = t >> 6;

    int c0 = t, c1 = t + 256;
    float dot0 = 0.f, dot1 = 0.f;
#pragma unroll
    for (int k = 0; k < KC; k++) {
        dot0 += part[(size_t)k * (Bb * Nn) + (size_t)b * Nn + c0];
        dot1 += part[(size_t)k * (Bb * Nn) + (size_t)b * Nn + c1];
    }
    float d0 = mm[c0] - 2.0f * dot0;
    float d1 = mm[c1] - 2.0f * dot1;

    float mn = fminf(d0, d1);
#pragma unroll
    for (int off = 32; off > 0; off >>= 1) mn = fminf(mn, __shfl_xor(mn, off));
    if (lane == 0) redW[w] = mn;
    __syncthreads();
    float thresh = fminf(fminf(redW[0], redW[1]), fminf(redW[2], redW[3])) + MARGIN;

    // ballot/prefix candidate build: group order (c0 waves 0-3, then c1 waves 0-3)
    bool f0 = (d0 <= thresh), f1 = (d1 <= thresh);
    unsigned long long mk0 = __ballot(f0), mk1 = __ballot(f1);
    if (lane == 0) { cntW[w] = (int)__popcll(mk0); cntW[4 + w] = (int)__popcll(mk1); }
    __syncthreads();
    int ncand = 0;
#pragma unroll
    for (int q = 0; q < 8; q++) ncand += cntW[q];
    int base0 = 0, baseF1 = cntW[0] + cntW[1] + cntW[2] + cntW[3];
#pragma unroll
    for (int q = 0; q < 4; q++) base0 += (q < w) ? cntW[q] : 0;
    int base1 = baseF1;
#pragma unroll
    for (int q = 0; q < 4; q++) base1 += (q < w) ? cntW[4 + q] : 0;
    unsigned long long ltm = (1ull << lane) - 1ull;
    if (f0) candList[base0 + (int)__popcll(mk0 & ltm)] = c0;
    if (f1) candList[base1 + (int)__popcll(mk1 & ltm)] = c1;
    __syncthreads();

    if (ncand == 1) {                 // uncontested coarse winner: exact dot unnecessary
        if (t == 0) assignF[b] = (float)candList[0];
        return;
    }

    // each wave handles candidates j = w, w+4, ... (full-row dot per wave);
    // Y row is L2-resident after the first candidate -- no staging needed.
    const float4* yr = (const float4*)(Y + (size_t)b * Dd);
    for (int j = w; j < ncand; j += 4) {
        int c = candList[j];
        const float4* mr = (const float4*)(M + (size_t)c * Dd);
        float p = 0.f;
#pragma unroll 8
        for (int u = 0; u < 32; u++) {
            float4 yv = yr[u * 64 + lane];
            float4 mv = mr[u * 64 + lane];
            p += yv.x * mv.x + yv.y * mv.y + yv.z * mv.z + yv.w * mv.w;
        }
#pragma unroll
        for (int off = 32; off > 0; off >>= 1) p += __shfl_xor(p, off);
        if (lane == 0) candD2[j] = mm[c] - 2.0f * p;
    }
    __syncthreads();

    if (t == 0) {       // index-ordered scan: deterministic regardless of list order
        float bestV = 3.4e38f;
        int bestI = 0x3fffffff;
        for (int j = 0; j < ncand; j++) {
            float d2e = candD2[j];
            int c = candList[j];
            if (d2e < bestV || (d2e == bestV && c < bestI)) { bestV = d2e; bestI = c; }
        }
        assignF[b] = (float)bestI;
    }
}

// ---------------- 4: closed-form EMA (exact to <=1e-5) -------------------------
// Grid (Nn, 4), 256 threads. Block (n,s) owns 2048-float slice s.
// All 4 waves redundantly scan assignF (wave-uniform results, no shared mem).
// The 32 assignF words are loaded into REGISTERS first (independent loads),
// then the ballot chain runs on registers (pure VALU).
// m_out = 0.001^k*m0 + 0.999*y[i1] + 0.000999*y[i2] + 9.99e-7*y[i3]
// sd_out = 0.999^k*sd0 ; p_out = p0 + k. Powers via binary exponentiation.
__global__ __launch_bounds__(256) void ema_closed(const float* __restrict__ Y,
                                                  const float* __restrict__ M0,
                                                  const float* __restrict__ SD0,
                                                  const float* __restrict__ P0,
                                                  const float* __restrict__ assignF,
                                                  float* __restrict__ m_out,
                                                  float* __restrict__ sd_out,
                                                  float* __restrict__ p_out) {
    const int n = blockIdx.x, s = blockIdx.y, t = threadIdx.x;
    const int lane = t & 63;

    // hoisted loads: fully unrolled -> static indices -> registers (rule #20)
    int ziv[32];
#pragma unroll
    for (int u = 0; u < 32; u++) ziv[u] = (int)assignF[u * 64 + lane];

    int k = 0, i1 = -1, i2 = -1, i3 = -1;
#pragma unroll
    for (int u = 0; u < 32; u++) {
        unsigned long long mask = __ballot(ziv[u] == n);
        int c = (int)__popcll(mask);
        if (c > 0) {                           // wave-uniform branch (ballot result)
            int b1 = 63 - (int)__builtin_clzll(mask);
            if (c == 1) { i3 = i2; i2 = i1; i1 = u * 64 + b1; }
            else {
                unsigned long long m2 = mask & ~(1ull << b1);
                int b2 = 63 - (int)__builtin_clzll(m2);
                if (c == 2) { i3 = i1; i2 = u * 64 + b2; i1 = u * 64 + b1; }
                else {
                    unsigned long long m3 = m2 & ~(1ull << b2);
                    int b3 = 63 - (int)__builtin_clzll(m3);
                    i3 = u * 64 + b3; i2 = u * 64 + b2; i1 = u * 64 + b1;
                }
            }
            k += c;
        }
    }

    // binary pow: 0.001^k (underflow->0 for large k: term negligible) and 0.999^k
    float pwm = 1.f, pws = 1.f;
    {
        float bm = 0.001f, bs = 0.999f;
        int e = k;
        while (e) {
            if (e & 1) { pwm *= bm; pws *= bs; }
            bm *= bm; bs *= bs; e >>= 1;
        }
    }

    const size_t b4 = (size_t)n * (Dd / 4) + (size_t)s * 512;   // float4 units
    const f32x4* m4 = (const f32x4*)M0 + b4;
    const f32x4* s4 = (const f32x4*)SD0 + b4;
    f32x4* mo = (f32x4*)m_out + b4;
    f32x4* so = (f32x4*)sd_out + b4;

    f32x4 ma = m4[t] * pwm;
    f32x4 mb = m4[t + 256] * pwm;
    if (k >= 1) {
        const f32x4* y = (const f32x4*)Y + (size_t)i1 * (Dd / 4) + (size_t)s * 512;
        ma += y[t] * 0.999f;      mb += y[t + 256] * 0.999f;
    }
    if (k >= 2) {
        const f32x4* y = (const f32x4*)Y + (size_t)i2 * (Dd / 4) + (size_t)s * 512;
        ma += y[t] * 0.000999f;   mb += y[t + 256] * 0.000999f;
    }
    if (k >= 3) {
        const f32x4* y = (const f32x4*)Y + (size_t)i3 * (Dd / 4) + (size_t)s * 512;
        ma += y[t] * 9.99e-07f;   mb += y[t + 256] * 9.99e-07f;
    }
    mo[t] = ma;  mo[t + 256] = mb;
    so[t] = s4[t] * pws;  so[t + 256] = s4[t + 256] * pws;
    if (s == 0 && t == 0) p_out[n] = P0[n] + (float)k;
}

extern "C" void kernel_launch(void* const* d_in, const int* in_sizes, int n_in,
                              void* d_out, int out_size, void* d_ws, size_t ws_size,
                              hipStream_t stream) {
    const float* y  = (const float*)d_in[0];
    const float* m  = (const float*)d_in[1];
    const float* sd = (const float*)d_in[2];
    const float* p  = (const float*)d_in[3];

    float* out     = (float*)d_out;
    float* m_out   = out;                       // partials k=0..3 live here pre-rescore
    float* sd_out  = out + 4194304;             // partials k=4..7 live here pre-rescore
    float* p_out   = out + 8388608;             // also: mm norms (dead after rescore)
    float* assignF = out + 8389120;
    float* part    = out;                       // 8 x 1M floats = m+sd regions exactly

    m_norms    <<<Nn, 256, 0, stream>>>(m, p_out);
    gemm_coarse<<<dim3(256), 1024, 0, stream>>>(y, m, part);
    rescore    <<<Bb, 256, 0, stream>>>(y, m, part, p_out, assignF);
    ema_closed <<<dim3(Nn, 4), 256, 0, stream>>>(y, m, sd, p, assignF, m_out, sd_out, p_out);
}